// Round 2
// baseline (155.037 us; speedup 1.0000x reference)
//
#include <hip/hip_runtime.h>

typedef _Float16 half8 __attribute__((ext_vector_type(8)));
typedef float floatx4 __attribute__((ext_vector_type(4)));

#define IN_DIM 256
#define OUT_DIM 256
#define M_TILE 64

// Quantize weight -> f16 in MFMA-A-fragment-permuted order:
//   perm[((ct*8 + ks)*64 + lane)*8 + e] = rne(W[ct*16 + (lane&15)][ks*32 + (lane>>4)*8 + e] * 100)
// so the gemm's A-frag load for (col-tile ct, k-step ks) is one fully-coalesced
// 16B/lane global_load_dwordx4. Also quantizes bias and writes the scalar output.
__global__ void quant_kernel(const float* __restrict__ w,
                             const float* __restrict__ bias,
                             const float* __restrict__ in_scale,
                             _Float16* __restrict__ wqp,
                             float* __restrict__ bq,
                             float* __restrict__ out_scalar) {
    int t = blockIdx.x * blockDim.x + threadIdx.x;   // 8192 threads, 8 elems each
    if (t < (OUT_DIM * IN_DIM) / 8) {
        int lane = t & 63;
        int ks   = (t >> 6) & 7;
        int ct   = t >> 9;
        int row  = ct * 16 + (lane & 15);
        int k0   = ks * 32 + (lane >> 4) * 8;
        const float* src = w + row * IN_DIM + k0;    // 32B contiguous per thread
        half8 h;
#pragma unroll
        for (int e = 0; e < 8; ++e)
            h[e] = (_Float16)rintf(src[e] * 100.0f); // jnp.round = round-half-even
        *((half8*)wqp + t) = h;
    }
    if (t < OUT_DIM) {
        float s2 = in_scale[0] * 100.0f;
        bq[t] = rintf(bias[t] * s2);
    }
    if (t == 0 && out_scalar != nullptr)
        out_scalar[0] = in_scale[0] * 100.0f;
}

// Per block: 64 batch rows x 256 out cols, NO LDS, no barrier.
// B-fragments loaded straight from global: for (j,ks) lane reads
// cx[m0 + j*16 + (lane&15)][ks*32 + (lane>>4)*8 .. +8) = 32B contiguous;
// a full wave covers 16 rows x 128B contiguous -> no over-fetch, L2/L3 absorbs
// the 4x per-block re-read across waves. int->f16 cvt in-register (values <200).
// A = W (permuted, coalesced 16B/lane). D: row(quad*4+reg)=out col,
// col(lane&15)=batch row -> float4 stores of 4 consecutive out cols per lane.
__global__ __launch_bounds__(256, 4) void gemm_kernel(const int* __restrict__ cx,
                                                      const _Float16* __restrict__ wqp,
                                                      const float* __restrict__ bq,
                                                      float* __restrict__ out) {
    const int t    = threadIdx.x;
    const int wave = t >> 6;
    const int lane = t & 63;
    const int m16  = lane & 15;
    const int quad = lane >> 4;
    const size_t m0 = (size_t)blockIdx.x * M_TILE;

    floatx4 acc[4][4] = {};   // [i: out-col tile][j: batch-row tile]

    const half8* wbase = (const half8*)wqp;                    // units of 16B
    const int* crow = cx + (m0 + m16) * IN_DIM + quad * 8;     // + j*16*IN_DIM + ks*32

#pragma unroll
    for (int ks = 0; ks < 8; ++ks) {
        half8 afr[4];
#pragma unroll
        for (int i = 0; i < 4; ++i)          // coalesced: consecutive lanes -> consecutive 16B
            afr[i] = wbase[((wave * 4 + i) * 8 + ks) * 64 + lane];

        half8 bfrg[4];
#pragma unroll
        for (int j = 0; j < 4; ++j) {
            const int* p = crow + j * 16 * IN_DIM + ks * 32;
            int4 v0 = *(const int4*)p;
            int4 v1 = *(const int4*)(p + 4);
            half8 h;
            h[0] = (_Float16)(short)v0.x; h[1] = (_Float16)(short)v0.y;
            h[2] = (_Float16)(short)v0.z; h[3] = (_Float16)(short)v0.w;
            h[4] = (_Float16)(short)v1.x; h[5] = (_Float16)(short)v1.y;
            h[6] = (_Float16)(short)v1.z; h[7] = (_Float16)(short)v1.w;
            bfrg[j] = h;
        }

#pragma unroll
        for (int i = 0; i < 4; ++i)
#pragma unroll
            for (int j = 0; j < 4; ++j)
                acc[i][j] = __builtin_amdgcn_mfma_f32_16x16x32_f16(afr[i], bfrg[j], acc[i][j], 0, 0, 0);
    }

    // ---- epilogue: lane owns 4 consecutive out cols -> float4 stores ----
#pragma unroll
    for (int i = 0; i < 4; ++i) {
        int col = wave * 64 + i * 16 + quad * 4;
        floatx4 bv = *(const floatx4*)(bq + col);
#pragma unroll
        for (int j = 0; j < 4; ++j) {
            size_t row = m0 + j * 16 + m16;
            floatx4 v = acc[i][j] + bv;
            __builtin_nontemporal_store(v, (floatx4*)(out + row * OUT_DIM + col));
        }
    }
}

extern "C" void kernel_launch(void* const* d_in, const int* in_sizes, int n_in,
                              void* d_out, int out_size, void* d_ws, size_t ws_size,
                              hipStream_t stream) {
    const int*   cx       = (const int*)d_in[0];
    const float* w        = (const float*)d_in[1];
    const float* bias     = (const float*)d_in[2];
    const float* in_scale = (const float*)d_in[3];
    float* out = (float*)d_out;

    _Float16* wqp = (_Float16*)d_ws;                              // 128 KB, permuted
    float*    bq  = (float*)((char*)d_ws + OUT_DIM * IN_DIM * 2); // 1 KB

    const int rows = in_sizes[0] / IN_DIM;          // 65536
    const size_t gemm_elems = (size_t)rows * OUT_DIM;
    float* out_scalar = ((size_t)out_size > gemm_elems) ? (out + gemm_elems) : nullptr;

    quant_kernel<<<32, 256, 0, stream>>>(w, bias, in_scale, wqp, bq, out_scalar);
    gemm_kernel<<<rows / M_TILE, 256, 0, stream>>>(cx, wqp, bq, out);
}

// Round 3
// 129.925 us; speedup vs baseline: 1.1933x; 1.1933x over previous
//
#include <hip/hip_runtime.h>

typedef _Float16 half8 __attribute__((ext_vector_type(8)));
typedef _Float16 half4 __attribute__((ext_vector_type(4)));
typedef float floatx4 __attribute__((ext_vector_type(4)));

#define IN_DIM 256
#define OUT_DIM 256
#define M_TILE 32
#define ROWSTR 264  // 256 + 8 f16 pad

// Quantize weight -> f16 in MFMA-A-fragment-permuted order:
//   perm[((ct*8 + ks)*64 + lane)*8 + e] = rne(W[ct*16 + (lane&15)][ks*32 + (lane>>4)*8 + e] * 100)
// so the gemm's A-frag load for (col-tile ct, k-step ks) is one fully-coalesced
// 16B/lane global_load_dwordx4. Also quantizes bias and writes the scalar output.
__global__ void quant_kernel(const float* __restrict__ w,
                             const float* __restrict__ bias,
                             const float* __restrict__ in_scale,
                             _Float16* __restrict__ wqp,
                             float* __restrict__ bq,
                             float* __restrict__ out_scalar) {
    int t = blockIdx.x * blockDim.x + threadIdx.x;   // 8192 threads, 8 elems each
    if (t < (OUT_DIM * IN_DIM) / 8) {
        int lane = t & 63;
        int ks   = (t >> 6) & 7;
        int ct   = t >> 9;
        int row  = ct * 16 + (lane & 15);
        int k0   = ks * 32 + (lane >> 4) * 8;
        const float* src = w + row * IN_DIM + k0;    // 32B contiguous per thread
        half8 h;
#pragma unroll
        for (int e = 0; e < 8; ++e)
            h[e] = (_Float16)rintf(src[e] * 100.0f); // jnp.round = round-half-even
        *((half8*)wqp + t) = h;
    }
    if (t < OUT_DIM) {
        float s2 = in_scale[0] * 100.0f;
        bq[t] = rintf(bias[t] * s2);
    }
    if (t == 0 && out_scalar != nullptr)
        out_scalar[0] = in_scale[0] * 100.0f;
}

// Round-0 structure (LDS staging + barrier) with M_TILE 64 -> 32:
// 2048 blocks instead of 1024, ~6-8 blocks/CU instead of 4, so block phases
// (stage / compute / write) overlap ACROSS blocks instead of convoying.
// Per block: 32 batch rows x 256 out cols. A = W (permuted, coalesced global L2),
// B = c_x (staged int32->f16 via LDS). D: row(quad*4+reg)=out col, col(lane&15)=batch row
// -> float4 stores of 4 consecutive out cols per lane.
__global__ __launch_bounds__(256, 6) void gemm_kernel(const int* __restrict__ cx,
                                                      const _Float16* __restrict__ wqp,
                                                      const float* __restrict__ bq,
                                                      float* __restrict__ out) {
    __shared__ _Float16 cT[M_TILE * ROWSTR];

    const int t = threadIdx.x;
    const size_t m0 = (size_t)blockIdx.x * M_TILE;

    // ---- stage 32 rows x 256 int32 -> f16, coalesced int4 loads ----
    const int* cbase = cx + m0 * IN_DIM;
#pragma unroll
    for (int i = 0; i < 8; ++i) {
        int flat = i * 1024 + t * 4;
        int4 v = *(const int4*)(cbase + flat);
        int row = flat >> 8;
        int col = flat & 255;
        half4 h;
        h.x = (_Float16)v.x; h.y = (_Float16)v.y;
        h.z = (_Float16)v.z; h.w = (_Float16)v.w;
        *(half4*)&cT[row * ROWSTR + col] = h;
    }
    __syncthreads();

    const int wave = t >> 6;
    const int lane = t & 63;
    const int m16  = lane & 15;
    const int quad = lane >> 4;

    floatx4 acc[4][2] = {};   // [i: out-col tile][j: batch-row tile]

    const half8* wbase = (const half8*)wqp;   // units of 16B
#pragma unroll
    for (int ks = 0; ks < 8; ++ks) {
        half8 afr[4], bfr[2];
#pragma unroll
        for (int i = 0; i < 4; ++i)          // coalesced: consecutive lanes -> consecutive 16B
            afr[i] = wbase[((wave * 4 + i) * 8 + ks) * 64 + lane];
        const int kb = ks * 32 + quad * 8;
#pragma unroll
        for (int j = 0; j < 2; ++j)          // ds_read_b128, bank-balanced
            bfr[j] = *(const half8*)&cT[(j * 16 + m16) * ROWSTR + kb];
#pragma unroll
        for (int i = 0; i < 4; ++i)
#pragma unroll
            for (int j = 0; j < 2; ++j)
                acc[i][j] = __builtin_amdgcn_mfma_f32_16x16x32_f16(afr[i], bfr[j], acc[i][j], 0, 0, 0);
    }

    // ---- epilogue: lane owns 4 consecutive out cols -> float4 stores ----
#pragma unroll
    for (int i = 0; i < 4; ++i) {
        int col = wave * 64 + i * 16 + quad * 4;
        floatx4 bv = *(const floatx4*)(bq + col);
#pragma unroll
        for (int j = 0; j < 2; ++j) {
            size_t row = m0 + j * 16 + m16;
            floatx4 v = acc[i][j] + bv;
            __builtin_nontemporal_store(v, (floatx4*)(out + row * OUT_DIM + col));
        }
    }
}

extern "C" void kernel_launch(void* const* d_in, const int* in_sizes, int n_in,
                              void* d_out, int out_size, void* d_ws, size_t ws_size,
                              hipStream_t stream) {
    const int*   cx       = (const int*)d_in[0];
    const float* w        = (const float*)d_in[1];
    const float* bias     = (const float*)d_in[2];
    const float* in_scale = (const float*)d_in[3];
    float* out = (float*)d_out;

    _Float16* wqp = (_Float16*)d_ws;                              // 128 KB, permuted
    float*    bq  = (float*)((char*)d_ws + OUT_DIM * IN_DIM * 2); // 1 KB

    const int rows = in_sizes[0] / IN_DIM;          // 65536
    const size_t gemm_elems = (size_t)rows * OUT_DIM;
    float* out_scalar = ((size_t)out_size > gemm_elems) ? (out + gemm_elems) : nullptr;

    quant_kernel<<<32, 256, 0, stream>>>(w, bias, in_scale, wqp, bq, out_scalar);
    gemm_kernel<<<rows / M_TILE, 256, 0, stream>>>(cx, wqp, bq, out);
}

// Round 5
// 123.369 us; speedup vs baseline: 1.2567x; 1.0531x over previous
//
#include <hip/hip_runtime.h>

typedef _Float16 half8 __attribute__((ext_vector_type(8)));
typedef _Float16 half4 __attribute__((ext_vector_type(4)));
typedef float floatx4 __attribute__((ext_vector_type(4)));

#define IN_DIM 256
#define OUT_DIM 256
#define M_TILE 64
#define ROWSTR 264  // 256 + 8 f16 pad

// Quantize weight -> f16 in MFMA-A-fragment-permuted order:
//   perm[((ct*8 + ks)*64 + lane)*8 + e] = rne(W[ct*16 + (lane&15)][ks*32 + (lane>>4)*8 + e] * 100)
// so the gemm's A-frag load for (col-tile ct, k-step ks) is one fully-coalesced
// 16B/lane global_load_dwordx4. Also quantizes bias and writes the scalar output.
__global__ void quant_kernel(const float* __restrict__ w,
                             const float* __restrict__ bias,
                             const float* __restrict__ in_scale,
                             _Float16* __restrict__ wqp,
                             float* __restrict__ bq,
                             float* __restrict__ out_scalar) {
    int t = blockIdx.x * blockDim.x + threadIdx.x;   // 8192 threads, 8 elems each
    if (t < (OUT_DIM * IN_DIM) / 8) {
        int lane = t & 63;
        int ks   = (t >> 6) & 7;
        int ct   = t >> 9;
        int row  = ct * 16 + (lane & 15);
        int k0   = ks * 32 + (lane >> 4) * 8;
        const float* src = w + row * IN_DIM + k0;    // 32B contiguous per thread
        half8 h;
#pragma unroll
        for (int e = 0; e < 8; ++e)
            h[e] = (_Float16)rintf(src[e] * 100.0f); // jnp.round = round-half-even
        *((half8*)wqp + t) = h;
    }
    if (t < OUT_DIM) {
        float s2 = in_scale[0] * 100.0f;
        bq[t] = rintf(bias[t] * s2);
    }
    if (t == 0 && out_scalar != nullptr)
        out_scalar[0] = in_scale[0] * 100.0f;
}

// ---- helpers shared by both pipeline stages ----
__device__ __forceinline__ void compute_tile(const _Float16* __restrict__ cbuf,
                                             const half8* __restrict__ wbase,
                                             int wave, int lane, int m16, int quad,
                                             floatx4 acc[4][4]) {
#pragma unroll
    for (int ks = 0; ks < 8; ++ks) {
        half8 afr[4], bfr[4];
#pragma unroll
        for (int i = 0; i < 4; ++i)          // coalesced: consecutive lanes -> consecutive 16B (L2-hit)
            afr[i] = wbase[((wave * 4 + i) * 8 + ks) * 64 + lane];
        const int kb = ks * 32 + quad * 8;
#pragma unroll
        for (int j = 0; j < 4; ++j)          // ds_read_b128, bank-balanced via ROWSTR pad
            bfr[j] = *(const half8*)&cbuf[(j * 16 + m16) * ROWSTR + kb];
#pragma unroll
        for (int i = 0; i < 4; ++i)
#pragma unroll
            for (int j = 0; j < 4; ++j)
                acc[i][j] = __builtin_amdgcn_mfma_f32_16x16x32_f16(afr[i], bfr[j], acc[i][j], 0, 0, 0);
    }
}

__device__ __forceinline__ void store_tile(float* __restrict__ out,
                                           const float* __restrict__ bq,
                                           size_t m0, int wave, int m16, int quad,
                                           floatx4 acc[4][4]) {
#pragma unroll
    for (int i = 0; i < 4; ++i) {
        int col = wave * 64 + i * 16 + quad * 4;
        floatx4 bv = *(const floatx4*)(bq + col);
#pragma unroll
        for (int j = 0; j < 4; ++j) {
            size_t row = m0 + j * 16 + m16;
            floatx4 v = acc[i][j] + bv;
            *(floatx4*)(out + row * OUT_DIM + col) = v;   // plain stores: best WRITE_SIZE (R0)
        }
    }
}

// 2-tile software pipeline per block, double-buffered LDS:
//   stage(T0) | barrier | issue T1 global loads (pinned early) | compute(T0)
//   | cvt+ds_write(T1) | barrier | store(T0) | compute(T1) | store(T1)
// T1's L3 load latency hides under T0's MFMA; T0's HBM stores hide under T1's compute.
// grid = ntiles/2 blocks, 2 blocks/CU (67.6KB LDS), ~200 VGPR -> 2 waves/SIMD.
__global__ __launch_bounds__(256, 2) void gemm_kernel(const int* __restrict__ cx,
                                                      const _Float16* __restrict__ wqp,
                                                      const float* __restrict__ bq,
                                                      float* __restrict__ out) {
    __shared__ _Float16 cT[2][M_TILE * ROWSTR];

    const int t    = threadIdx.x;
    const int wave = t >> 6;
    const int lane = t & 63;
    const int m16  = lane & 15;
    const int quad = lane >> 4;

    const size_t m0 = (size_t)blockIdx.x * M_TILE;
    const size_t m1 = m0 + (size_t)gridDim.x * M_TILE;
    const half8* wbase = (const half8*)wqp;

    // ---- stage T0: 64 rows x 256 int32 -> f16, coalesced int4 loads ----
    {
        const int* cbase = cx + m0 * IN_DIM;
#pragma unroll
        for (int i = 0; i < 16; ++i) {
            int flat = i * 1024 + t * 4;
            int4 v = *(const int4*)(cbase + flat);
            half4 h;
            h.x = (_Float16)v.x; h.y = (_Float16)v.y;
            h.z = (_Float16)v.z; h.w = (_Float16)v.w;
            *(half4*)&cT[0][(flat >> 8) * ROWSTR + (flat & 255)] = h;
        }
    }
    __syncthreads();

    // ---- issue T1 global loads into registers, pinned BEFORE compute(T0) ----
    int4 st[16];
    {
        const int* cbase = cx + m1 * IN_DIM;
#pragma unroll
        for (int i = 0; i < 16; ++i)
            st[i] = *(const int4*)(cbase + i * 1024 + t * 4);
    }
    __builtin_amdgcn_sched_barrier(0);   // keep the loads issued here, not sunk past compute

    // ---- compute T0 (MFMA hides T1 load latency) ----
    floatx4 acc[4][4] = {};
    compute_tile(cT[0], wbase, wave, lane, m16, quad, acc);

    // ---- cvt + ds_write T1 into buf1 (waits on the in-flight loads here) ----
#pragma unroll
    for (int i = 0; i < 16; ++i) {
        int flat = i * 1024 + t * 4;
        half4 h;
        h.x = (_Float16)st[i].x; h.y = (_Float16)st[i].y;
        h.z = (_Float16)st[i].z; h.w = (_Float16)st[i].w;
        *(half4*)&cT[1][(flat >> 8) * ROWSTR + (flat & 255)] = h;
    }
    __syncthreads();

    // ---- store T0 (stores drain while T1 computes) ----
    store_tile(out, bq, m0, wave, m16, quad, acc);

    // ---- compute + store T1 ----
    floatx4 acc2[4][4] = {};
    compute_tile(cT[1], wbase, wave, lane, m16, quad, acc2);
    store_tile(out, bq, m1, wave, m16, quad, acc2);
}

extern "C" void kernel_launch(void* const* d_in, const int* in_sizes, int n_in,
                              void* d_out, int out_size, void* d_ws, size_t ws_size,
                              hipStream_t stream) {
    const int*   cx       = (const int*)d_in[0];
    const float* w        = (const float*)d_in[1];
    const float* bias     = (const float*)d_in[2];
    const float* in_scale = (const float*)d_in[3];
    float* out = (float*)d_out;

    _Float16* wqp = (_Float16*)d_ws;                              // 128 KB, permuted
    float*    bq  = (float*)((char*)d_ws + OUT_DIM * IN_DIM * 2); // 1 KB

    const int rows = in_sizes[0] / IN_DIM;          // 65536
    const size_t gemm_elems = (size_t)rows * OUT_DIM;
    float* out_scalar = ((size_t)out_size > gemm_elems) ? (out + gemm_elems) : nullptr;

    const int ntiles = rows / M_TILE;               // 1024
    quant_kernel<<<32, 256, 0, stream>>>(w, bias, in_scale, wqp, bq, out_scalar);
    gemm_kernel<<<ntiles / 2, 256, 0, stream>>>(cx, wqp, bq, out);
}